// Round 1
// baseline (2444.868 us; speedup 1.0000x reference)
//
#include <hip/hip_runtime.h>

#define B 128
#define S 16
#define E 512
#define R 1000
#define K3 1536
#define NW0 1920   // init worklist: 128 b * 15 pairs
#define NWS 256    // per-step worklist: 128 b * 2 entries
#define SCALE 0.04419417382415922f

static __device__ __forceinline__ float sigm(float x) { return 1.f / (1.f + expf(-x)); }

// ---------- block reductions (256 threads) ----------
static __device__ __forceinline__ float brsum(float v, float* sb) {
  int tid = threadIdx.x;
  sb[tid] = v; __syncthreads();
  for (int s = 128; s > 0; s >>= 1) {
    if (tid < s) sb[tid] += sb[tid + s];
    __syncthreads();
  }
  float r = sb[0]; __syncthreads();
  return r;
}
static __device__ __forceinline__ float brmax(float v, float* sb) {
  int tid = threadIdx.x;
  sb[tid] = v; __syncthreads();
  for (int s = 128; s > 0; s >>= 1) {
    if (tid < s) sb[tid] = fmaxf(sb[tid], sb[tid + s]);
    __syncthreads();
  }
  float r = sb[0]; __syncthreads();
  return r;
}

#define TILE_FMA \
  _Pragma("unroll") \
  for (int k = 0; k < 16; ++k) { \
    float4 a4 = *(const float4*)&As[k][ty * 4]; \
    float4 w4 = *(const float4*)&Ws[k][tx * 4]; \
    acc[0][0] = fmaf(a4.x, w4.x, acc[0][0]); acc[0][1] = fmaf(a4.x, w4.y, acc[0][1]); \
    acc[0][2] = fmaf(a4.x, w4.z, acc[0][2]); acc[0][3] = fmaf(a4.x, w4.w, acc[0][3]); \
    acc[1][0] = fmaf(a4.y, w4.x, acc[1][0]); acc[1][1] = fmaf(a4.y, w4.y, acc[1][1]); \
    acc[1][2] = fmaf(a4.y, w4.z, acc[1][2]); acc[1][3] = fmaf(a4.y, w4.w, acc[1][3]); \
    acc[2][0] = fmaf(a4.z, w4.x, acc[2][0]); acc[2][1] = fmaf(a4.z, w4.y, acc[2][1]); \
    acc[2][2] = fmaf(a4.z, w4.z, acc[2][2]); acc[2][3] = fmaf(a4.z, w4.w, acc[2][3]); \
    acc[3][0] = fmaf(a4.w, w4.x, acc[3][0]); acc[3][1] = fmaf(a4.w, w4.y, acc[3][1]); \
    acc[3][2] = fmaf(a4.w, w4.z, acc[3][2]); acc[3][3] = fmaf(a4.w, w4.w, acc[3][3]); \
  }

// ---------- init: pos identity + full worklist ----------
__global__ __launch_bounds__(256) void k_initwl(int* __restrict__ pos,
                                                int* __restrict__ wlb,
                                                int* __restrict__ wlL,
                                                int* __restrict__ wlR) {
  int idx = blockIdx.x * 256 + threadIdx.x;
  if (idx < B * 16) pos[idx] = idx & 15;
  if (idx < NW0) {
    wlb[idx] = idx / 15;
    int i = idx % 15;
    wlL[idx] = i;
    wlR[idx] = i + 1;
  }
}

// ---------- 64x64 LDS transpose: dst[c*ldd + r] = src[r*Cc + c] ----------
// grid = (Cc/64, Rows/64)
__global__ __launch_bounds__(256) void k_tr(const float* __restrict__ src, int Cc,
                                            float* __restrict__ dst, int ldd) {
  __shared__ float t[64][65];
  int tid = threadIdx.x, tx = tid & 15, ty = tid >> 4;
  int rb = blockIdx.y * 64, cb = blockIdx.x * 64;
#pragma unroll
  for (int i = 0; i < 4; ++i) {
    int r = rb + ty + i * 16;
    float4 v = *(const float4*)(src + (size_t)r * Cc + cb + tx * 4);
    t[ty + i * 16][tx * 4 + 0] = v.x; t[ty + i * 16][tx * 4 + 1] = v.y;
    t[ty + i * 16][tx * 4 + 2] = v.z; t[ty + i * 16][tx * 4 + 3] = v.w;
  }
  __syncthreads();
#pragma unroll
  for (int i = 0; i < 4; ++i) {
    int c = cb + ty + i * 16;
    float4 v;
    v.x = t[tx * 4 + 0][ty + i * 16]; v.y = t[tx * 4 + 1][ty + i * 16];
    v.z = t[tx * 4 + 2][ty + i * 16]; v.w = t[tx * 4 + 3][ty + i * 16];
    *(float4*)(dst + (size_t)c * ldd + rb + tx * 4) = v;
  }
}

// ---------- generic tiled gemm: C[m,n] = scale*sum_k A[m*lda+k]*W[n*K+k] (+bias[n])
__global__ __launch_bounds__(256) void k_gemm(const float* __restrict__ A, int lda, int M,
                                              const float* __restrict__ W, int N, int K,
                                              const float* __restrict__ bias, float scale,
                                              float* __restrict__ C, int ldc) {
  __shared__ float As[16][64];
  __shared__ float Ws[16][64];
  int tid = threadIdx.x;
  int mBase = blockIdx.y * 64;
  int nBase = blockIdx.x * 64;
  int tx = tid & 15, ty = tid >> 4;
  int li = tid & 63;
  int lk = (tid >> 6) * 4;
  float acc[4][4] = {{0.f,0.f,0.f,0.f},{0.f,0.f,0.f,0.f},{0.f,0.f,0.f,0.f},{0.f,0.f,0.f,0.f}};
  int m = mBase + li;
  const float* Arow = (m < M) ? (A + (size_t)m * lda) : nullptr;
  int n = nBase + li;
  const float* Wrow = (n < N) ? (W + (size_t)n * K) : nullptr;

  float4 av = Arow ? *(const float4*)(Arow + lk) : make_float4(0.f, 0.f, 0.f, 0.f);
  float4 wv = Wrow ? *(const float4*)(Wrow + lk) : make_float4(0.f, 0.f, 0.f, 0.f);

  for (int k0 = 0; k0 < K; k0 += 16) {
    As[lk + 0][li] = av.x; As[lk + 1][li] = av.y;
    As[lk + 2][li] = av.z; As[lk + 3][li] = av.w;
    Ws[lk + 0][li] = wv.x; Ws[lk + 1][li] = wv.y;
    Ws[lk + 2][li] = wv.z; Ws[lk + 3][li] = wv.w;
    __syncthreads();
    if (k0 + 16 < K) {
      av = Arow ? *(const float4*)(Arow + k0 + 16 + lk) : make_float4(0.f, 0.f, 0.f, 0.f);
      wv = Wrow ? *(const float4*)(Wrow + k0 + 16 + lk) : make_float4(0.f, 0.f, 0.f, 0.f);
    }
    TILE_FMA
    __syncthreads();
  }
#pragma unroll
  for (int r = 0; r < 4; ++r) {
    int mm = mBase + ty * 4 + r;
    if (mm >= M) continue;
#pragma unroll
    for (int c = 0; c < 4; ++c) {
      int nn = nBase + tx * 4 + c;
      if (nn >= N) continue;
      float v = acc[r][c] * scale;
      if (bias) v += bias[nn];
      C[(size_t)mm * ldc + nn] = v;
    }
  }
}

// ---------- setup misc: zero Wbig pad rows, v12, c0, gb ----------
__global__ __launch_bounds__(256) void k_misc(float* __restrict__ Wbig,
                                              const float* __restrict__ WqT,
                                              const float* __restrict__ WkT,
                                              const float* __restrict__ bq,
                                              const float* __restrict__ bk,
                                              const float* __restrict__ KREL,
                                              float* __restrict__ v12,
                                              float* __restrict__ c0s,
                                              float* __restrict__ gb) {
  __shared__ float sb[256];
  int blk = blockIdx.x, tid = threadIdx.x;
  if (blk < 24) {
    for (int n = tid; n < K3; n += 256) Wbig[(size_t)(1000 + blk) * K3 + n] = 0.f;
  } else if (blk < 26) {
    int i = (blk - 24) * 256 + tid;
    const float* wq = WqT + (size_t)i * E;
    const float* wk = WkT + (size_t)i * E;
    float s = 0.f;
    for (int e = 0; e < E; ++e) s += wq[e] * bk[e] + bq[e] * wk[e];
    v12[i] = s;
  } else if (blk == 26) {
    float p = 0.f;
    for (int e = tid; e < E; e += 256) p += bq[e] * bk[e];
    float s = brsum(p, sb);
    if (tid == 0) c0s[0] = s;
  } else if (blk >= 28) {
    int r = (blk - 28) * 256 + tid;
    if (r < R) {
      const float* kr = KREL + (size_t)r * E;
      float s = 0.f;
      for (int e = 0; e < E; ++e) s += bq[e] * kr[e];
      gb[r] = s;
    }
  }
}

// ---------- GI init: GI[row] = EW[token[row]] + b_ih (gather, no gemm) ----------
__global__ __launch_bounds__(256) void k_giinit(const int* __restrict__ tokens,
                                                const float* __restrict__ Wbig,
                                                const float* __restrict__ bih,
                                                float* __restrict__ GI) {
  int row = blockIdx.x;
  int tok = tokens[row];
  const float4* src = (const float4*)(Wbig + (size_t)tok * K3);
  const float4* bv = (const float4*)bih;
  float4* dst = (float4*)(GI + (size_t)row * K3);
  for (int i = threadIdx.x; i < K3 / 4; i += 256) {
    float4 a = src[i], b = bv[i];
    dst[i] = make_float4(a.x + b.x, a.y + b.y, a.z + b.z, a.w + b.w);
  }
}

// ---------- GHC gemm with h1 computed on the fly from GI (fused k_h1c) ----------
// GHC[w,n] = sum_e h1(GI[src(w)],e) * Whh[n,e] + bhh[n]; grid (24, M/64)
__global__ __launch_bounds__(256) void k_ghc(const int* __restrict__ wlb,
                                             const int* __restrict__ wlL,
                                             const float* __restrict__ GI,
                                             const float* __restrict__ bhh,
                                             const float* __restrict__ Whh,
                                             float* __restrict__ GHC, int M) {
  __shared__ float As[16][64];
  __shared__ float Ws[16][64];
  int tid = threadIdx.x;
  int nBase = blockIdx.x * 64;
  int mBase = blockIdx.y * 64;
  int tx = tid & 15, ty = tid >> 4;
  int li = tid & 63;
  int lk = (tid >> 6) * 4;
  int m = mBase + li;
  int src = (m < M) ? (wlb[m] * 16 + wlL[m]) : 0;
  const float* gi = GI + (size_t)src * K3;
  const float* Wrow = Whh + (size_t)(nBase + li) * E;
  float acc[4][4] = {{0.f,0.f,0.f,0.f},{0.f,0.f,0.f,0.f},{0.f,0.f,0.f,0.f},{0.f,0.f,0.f,0.f}};
  for (int k0 = 0; k0 < E; k0 += 16) {
    int e = k0 + lk;
    float4 g0 = *(const float4*)(gi + e);
    float4 g1 = *(const float4*)(gi + E + e);
    float4 g2 = *(const float4*)(gi + 2 * E + e);
    float4 b0 = *(const float4*)(bhh + e);
    float4 b1 = *(const float4*)(bhh + E + e);
    float4 b2 = *(const float4*)(bhh + 2 * E + e);
    float h0, h1v, h2, h3;
    { float rr = sigm(g0.x + b0.x), zz = sigm(g1.x + b1.x);
      h0 = (1.f - zz) * tanhf(g2.x + rr * b2.x); }
    { float rr = sigm(g0.y + b0.y), zz = sigm(g1.y + b1.y);
      h1v = (1.f - zz) * tanhf(g2.y + rr * b2.y); }
    { float rr = sigm(g0.z + b0.z), zz = sigm(g1.z + b1.z);
      h2 = (1.f - zz) * tanhf(g2.z + rr * b2.z); }
    { float rr = sigm(g0.w + b0.w), zz = sigm(g1.w + b1.w);
      h3 = (1.f - zz) * tanhf(g2.w + rr * b2.w); }
    float4 wv = *(const float4*)(Wrow + k0 + lk);
    As[lk + 0][li] = h0; As[lk + 1][li] = h1v;
    As[lk + 2][li] = h2; As[lk + 3][li] = h3;
    Ws[lk + 0][li] = wv.x; Ws[lk + 1][li] = wv.y;
    Ws[lk + 2][li] = wv.z; Ws[lk + 3][li] = wv.w;
    __syncthreads();
    TILE_FMA
    __syncthreads();
  }
#pragma unroll
  for (int r = 0; r < 4; ++r) {
    int mm = mBase + ty * 4 + r;
    if (mm >= M) continue;
#pragma unroll
    for (int c = 0; c < 4; ++c) {
      int nn = nBase + tx * 4 + c;
      GHC[(size_t)mm * K3 + nn] = acc[r][c] + bhh[nn];
    }
  }
}

// ---------- pair + fc score (h1 recomputed inline) ----------
__global__ __launch_bounds__(256) void k_pairc(const int* __restrict__ wlb,
                                               const int* __restrict__ wlL,
                                               const int* __restrict__ wlR,
                                               const float* __restrict__ GI,
                                               const float* __restrict__ GHC,
                                               const float* __restrict__ bhh,
                                               const float* __restrict__ wfc,
                                               const float* __restrict__ bfc,
                                               float* __restrict__ PAIR,
                                               float* __restrict__ SCR) {
  __shared__ float sb[256];
  int w = blockIdx.x, tid = threadIdx.x;
  int b = wlb[w], ls = wlL[w], rs = wlR[w];
  const float* gr = GI + (size_t)(b * 16 + rs) * K3;
  const float* gl = GI + (size_t)(b * 16 + ls) * K3;
  const float* gh = GHC + (size_t)w * K3;
  float* p = PAIR + (size_t)(b * 16 + ls) * E;
  float part = 0.f;
  for (int e = tid; e < E; e += 256) {
    float r1 = sigm(gl[e] + bhh[e]);
    float z1 = sigm(gl[E + e] + bhh[E + e]);
    float h1 = (1.f - z1) * tanhf(gl[2 * E + e] + r1 * bhh[2 * E + e]);
    float r = sigm(gr[e] + gh[e]);
    float z = sigm(gr[E + e] + gh[E + e]);
    float n = tanhf(gr[2 * E + e] + r * gh[2 * E + e]);
    float pv = (1.f - z) * n + z * h1;
    p[e] = pv;
    part += pv * wfc[e];
  }
  float d = brsum(part, sb);
  if (tid == 0) SCR[b * 16 + ls] = sigm(d + bfc[0]);
}

// ---------- argmax + pos/worklist update (SP now read through xdst) ----------
__global__ __launch_bounds__(64) void k_sel(const float* __restrict__ SCR,
                                            int* __restrict__ pos, int P,
                                            int* __restrict__ xdst,
                                            int* __restrict__ wlb,
                                            int* __restrict__ wlL,
                                            int* __restrict__ wlR) {
  int b = blockIdx.x;
  if (threadIdx.x != 0) return;
  int L = P + 1;
  int lp[16];
  for (int i = 0; i < L; ++i) lp[i] = pos[b * 16 + i];
  float best = -1e30f; int sel = 0;
  for (int i = 0; i < P; ++i) {
    float v = SCR[b * 16 + lp[i]];
    if (v > best) { best = v; sel = i; }
  }
  int r1i = (sel + 2 < L) ? sel + 2 : L - 1;
  int l1 = lp[sel], r1 = lp[r1i];
  int l0 = (sel > 0) ? lp[sel - 1] : l1;
  int r0 = (sel > 0) ? lp[sel] : r1;
  wlb[2 * b] = b;     wlL[2 * b] = l0;     wlR[2 * b] = r0;
  wlb[2 * b + 1] = b; wlL[2 * b + 1] = l1; wlR[2 * b + 1] = r1;
  xdst[b] = b * 16 + l1;
  for (int i = sel + 1; i < L - 1; ++i) pos[b * 16 + i] = lp[i + 1];
}

// ---------- final select: xdst[b] = row of h2 ----------
__global__ __launch_bounds__(128) void k_finsel(const int* __restrict__ pos,
                                                int* __restrict__ xdst) {
  int b = threadIdx.x;
  if (b < B) xdst[b] = b * 16 + pos[b * 16];
}

// ---------- scores + bilinear-helper gemm: SCT[b, 0:1000]  = (SP.G2 + gb)*SCALE
//                                           SCT[b, 1000:1512] = SP.Mqk (raw)
// A rows via xdst indirection into PAIR. grid (24, 2)
__global__ __launch_bounds__(256) void k_qsc(const float* __restrict__ PAIR,
                                             const int* __restrict__ xdst,
                                             const float* __restrict__ Gbig,
                                             const float* __restrict__ gb,
                                             float* __restrict__ SCT) {
  __shared__ float As[16][64];
  __shared__ float Ws[16][64];
  int tid = threadIdx.x;
  int mBase = blockIdx.y * 64;
  int nBase = blockIdx.x * 64;
  int tx = tid & 15, ty = tid >> 4;
  int li = tid & 63;
  int lk = (tid >> 6) * 4;
  float acc[4][4] = {{0.f,0.f,0.f,0.f},{0.f,0.f,0.f,0.f},{0.f,0.f,0.f,0.f},{0.f,0.f,0.f,0.f}};
  const float* Arow = PAIR + (size_t)xdst[mBase + li] * E;
  int n = nBase + li;
  const float* Wrow = (n < 1512) ? (Gbig + (size_t)n * E) : nullptr;
  float4 av = *(const float4*)(Arow + lk);
  float4 wv = Wrow ? *(const float4*)(Wrow + lk) : make_float4(0.f, 0.f, 0.f, 0.f);
  for (int k0 = 0; k0 < E; k0 += 16) {
    As[lk + 0][li] = av.x; As[lk + 1][li] = av.y;
    As[lk + 2][li] = av.z; As[lk + 3][li] = av.w;
    Ws[lk + 0][li] = wv.x; Ws[lk + 1][li] = wv.y;
    Ws[lk + 2][li] = wv.z; Ws[lk + 3][li] = wv.w;
    __syncthreads();
    if (k0 + 16 < E) {
      av = *(const float4*)(Arow + k0 + 16 + lk);
      wv = Wrow ? *(const float4*)(Wrow + k0 + 16 + lk) : make_float4(0.f, 0.f, 0.f, 0.f);
    }
    TILE_FMA
    __syncthreads();
  }
#pragma unroll
  for (int r = 0; r < 4; ++r) {
    int mm = mBase + ty * 4 + r;
#pragma unroll
    for (int c = 0; c < 4; ++c) {
      int nn = nBase + tx * 4 + c;
      if (nn >= 1512) continue;
      float v = (nn < 1000) ? (acc[r][c] + gb[nn]) * SCALE : acc[r][c];
      SCT[(size_t)mm * K3 + nn] = v;
    }
  }
}

// ---------- softmax/entropy + A2 build + GI row init ----------
__global__ __launch_bounds__(256) void k_sm(const float* __restrict__ SCT,
                                            const float* __restrict__ PAIR,
                                            const int* __restrict__ xdst,
                                            const float* __restrict__ v12,
                                            const float* __restrict__ c0s,
                                            float* __restrict__ SC,
                                            float* __restrict__ A2,
                                            float* __restrict__ GI,
                                            const float* __restrict__ bih,
                                            float* __restrict__ LOSS, int t, int writeProb) {
  __shared__ float sb[256];
  int b = blockIdx.x, tid = threadIdx.x;
  const float* row = SCT + (size_t)b * K3;
  const float* sp = PAIR + (size_t)xdst[b] * E;
  // last score via bilinear: SP.Mqk.SP + v12.SP + c0, then * SCALE
  float part = 0.f;
  for (int i = tid; i < E; i += 256) part += sp[i] * (row[1000 + i] + v12[i]);
  float last = (brsum(part, sb) + c0s[0]) * SCALE;
  // scores -> regs
  float s[4];
  float ml = last;
#pragma unroll
  for (int q = 0; q < 4; ++q) {
    int j = tid + q * 256;
    float v = (j < 1000) ? row[j] : -1e30f;
    s[q] = v;
    ml = fmaxf(ml, v);
  }
  float mx = brmax(ml, sb);
  float zp = 0.f, sp1 = 0.f;
#pragma unroll
  for (int q = 0; q < 4; ++q) {
    int j = tid + q * 256;
    if (j < 1000) { float e = expf(s[q] - mx); zp += e; sp1 += e * s[q]; }
  }
  if (tid == 0) { float e = expf(last - mx); zp += e; sp1 += e * last; }
  float z = brsum(zp, sb);
  float s1 = brsum(sp1, sb);
  if (tid == 0) LOSS[b * 16 + t] = mx + logf(z) - s1 / z;
  for (int j = tid; j < 1001; j += 256)
    SC[(size_t)b * (R + 1) + j] = (j < 1000) ? row[j] : last;
  if (writeProb) {
    float inv = 1.f / z;
    float* a = A2 + (size_t)b * K3;
#pragma unroll
    for (int q = 0; q < 4; ++q) {
      int j = tid + q * 256;
      if (j < 1000) a[j] = expf(s[q] - mx) * inv;
    }
    if (tid < 24) a[1000 + tid] = 0.f;
    float pr = expf(last - mx) * inv;
    for (int i = tid; i < E; i += 256) a[1024 + i] = pr * sp[i];
    float* g = GI + (size_t)xdst[b] * K3;
    for (int n2 = tid; n2 < K3; n2 += 256) g[n2] = bih[n2];
  }
}

// ---------- fused merged+GI gemm, split-K atomic:
// GI[xdst[m], n] += sum_{k in slice} A2[m,k] * Wbig[k,n]   (Wbig k-major)
// grid (24, 2, 4)
__global__ __launch_bounds__(256) void k_giup(const float* __restrict__ A2,
                                              const float* __restrict__ Wbig,
                                              float* __restrict__ GI,
                                              const int* __restrict__ xdst) {
  __shared__ float As[16][64];
  __shared__ float Ws[16][64];
  int tid = threadIdx.x;
  int nBase = blockIdx.x * 64;
  int mBase = blockIdx.y * 64;
  int kbeg = blockIdx.z * 384;
  int tx = tid & 15, ty = tid >> 4;
  int li = tid & 63;
  int lk = (tid >> 6) * 4;
  int wr = tid >> 6;
  float acc[4][4] = {{0.f,0.f,0.f,0.f},{0.f,0.f,0.f,0.f},{0.f,0.f,0.f,0.f},{0.f,0.f,0.f,0.f}};
  const float* Arow = A2 + (size_t)(mBase + li) * K3;
  for (int k0 = kbeg; k0 < kbeg + 384; k0 += 16) {
    float4 av = *(const float4*)(Arow + k0 + lk);
    As[lk + 0][li] = av.x; As[lk + 1][li] = av.y;
    As[lk + 2][li] = av.z; As[lk + 3][li] = av.w;
#pragma unroll
    for (int j = 0; j < 4; ++j)
      Ws[wr * 4 + j][li] = Wbig[(size_t)(k0 + wr * 4 + j) * K3 + nBase + li];
    __syncthreads();
    TILE_FMA
    __syncthreads();
  }
#pragma unroll
  for (int r = 0; r < 4; ++r) {
    int mm = mBase + ty * 4 + r;
    size_t crow = (size_t)xdst[mm] * K3;
#pragma unroll
    for (int c = 0; c < 4; ++c) {
      int nn = nBase + tx * 4 + c;
      atomicAdd(&GI[crow + nn], acc[r][c]);
    }
  }
}

// ---------- final write (fp32 out: scores then losses, flat) ----------
__global__ __launch_bounds__(256) void k_writeout(const float* __restrict__ SC,
                                                  const float* __restrict__ LOSS,
                                                  float* __restrict__ out) {
  int idx = blockIdx.x * 256 + threadIdx.x;
  const int NS = B * (R + 1);
  if (idx < NS) {
    out[idx] = SC[idx];
  } else if (idx < NS + B * 16) {
    int r = idx - NS;
    int t = r & 15;
    out[idx] = (t == 14) ? 0.f : LOSS[r];
  }
}

extern "C" void kernel_launch(void* const* d_in, const int* in_sizes, int n_in,
                              void* d_out, int out_size, void* d_ws, size_t ws_size,
                              hipStream_t stream) {
  (void)in_sizes; (void)n_in; (void)out_size; (void)ws_size;
  const int* tokens = (const int*)d_in[0];
  const float* emb = (const float*)d_in[1];
  const float* W_ih = (const float*)d_in[2];
  const float* W_hh = (const float*)d_in[3];
  const float* b_ih = (const float*)d_in[4];
  const float* b_hh = (const float*)d_in[5];
  const float* w_fc = (const float*)d_in[6];
  const float* b_fc = (const float*)d_in[7];
  const float* Wq = (const float*)d_in[8];
  const float* bq = (const float*)d_in[9];
  const float* Wk = (const float*)d_in[10];
  const float* bk = (const float*)d_in[11];
  float* out = (float*)d_out;

  float* ws = (float*)d_ws;
  size_t o = 0;
  float* GI = ws + o;    o += (size_t)B * S * K3;      // 3.15M
  float* GHC = ws + o;   o += (size_t)NW0 * K3;        // 2.95M
  float* PAIR = ws + o;  o += (size_t)B * S * E;       // 1.05M
  float* Wbig = ws + o;  o += (size_t)K3 * K3;         // 2.36M  [EW | 0 | W_ih^T] k-major
  float* Gbig = ws + o;  o += (size_t)1512 * E;        // 0.77M  [G2(1000) ; Mqk(512)]
  float* KREL = ws + o;  o += (size_t)R * E;
  float* WqT = ws + o;   o += (size_t)E * E;
  float* WkT = ws + o;   o += (size_t)E * E;
  float* SCT = ws + o;   o += (size_t)B * K3;
  float* A2 = ws + o;    o += (size_t)B * K3;
  float* SC = ws + o;    o += (size_t)B * (R + 1);
  float* gb = ws + o;    o += 1024;
  float* v12 = ws + o;   o += 512;
  float* c0s = ws + o;   o += 16;
  float* LOSS = ws + o;  o += B * 16;
  float* SCR = ws + o;   o += B * 16;
  int* pos = (int*)(ws + o);  o += B * 16;
  int* wlb = (int*)(ws + o);  o += NW0;
  int* wlL = (int*)(ws + o);  o += NW0;
  int* wlR = (int*)(ws + o);  o += NW0;
  int* xdst = (int*)(ws + o); o += B;

  // ---- setup ----
  k_initwl<<<8, 256, 0, stream>>>(pos, wlb, wlL, wlR);
  k_tr<<<dim3(8, 8), 256, 0, stream>>>(Wq, E, WqT, E);
  k_tr<<<dim3(8, 8), 256, 0, stream>>>(Wk, E, WkT, E);
  k_tr<<<dim3(8, 24), 256, 0, stream>>>(W_ih, E, Wbig + (size_t)1024 * K3, K3);
  // KREL = emb[:1000] @ Wk^T + bk
  k_gemm<<<dim3(8, 16), 256, 0, stream>>>(emb, E, R, Wk, E, E, bk, 1.f, KREL, E);
  // Wbig rows 0..999 = EW = emb[:1000] @ W_ih^T
  k_gemm<<<dim3(24, 16), 256, 0, stream>>>(emb, E, R, W_ih, K3, E, nullptr, 1.f, Wbig, K3);
  // Gbig rows 0..999 = G2 = KREL @ Wq   (G2[r,i] = sum_e KREL[r,e] Wq[e,i])
  k_gemm<<<dim3(8, 16), 256, 0, stream>>>(KREL, E, R, WqT, E, E, nullptr, 1.f, Gbig, E);
  // Gbig rows 1000..1511 = Mqk = Wq^T @ Wk
  k_gemm<<<dim3(8, 8), 256, 0, stream>>>(WqT, E, E, WkT, E, E, nullptr, 1.f,
                                         Gbig + (size_t)1000 * E, E);
  k_misc<<<32, 256, 0, stream>>>(Wbig, WqT, WkT, bq, bk, KREL, v12, c0s, gb);
  // GI init = gather EW rows by token + b_ih (replaces embed + big gemm)
  k_giinit<<<B * S, 256, 0, stream>>>(tokens, Wbig, b_ih, GI);
  k_ghc<<<dim3(24, 30), 256, 0, stream>>>(wlb, wlL, GI, b_hh, W_hh, GHC, NW0);
  k_pairc<<<NW0, 256, 0, stream>>>(wlb, wlL, wlR, GI, GHC, b_hh, w_fc, b_fc, PAIR, SCR);

  // ---- 14 merge steps ----
  for (int t = 0; t < 14; ++t) {
    int P = 15 - t;
    k_sel<<<B, 64, 0, stream>>>(SCR, pos, P, xdst, wlb, wlL, wlR);
    k_qsc<<<dim3(24, 2), 256, 0, stream>>>(PAIR, xdst, Gbig, gb, SCT);
    k_sm<<<B, 256, 0, stream>>>(SCT, PAIR, xdst, v12, c0s, SC, A2, GI, b_ih, LOSS, t, 1);
    k_giup<<<dim3(24, 2, 4), 256, 0, stream>>>(A2, Wbig, GI, xdst);
    k_ghc<<<dim3(24, 4), 256, 0, stream>>>(wlb, wlL, GI, b_hh, W_hh, GHC, NWS);
    k_pairc<<<NWS, 256, 0, stream>>>(wlb, wlL, wlR, GI, GHC, b_hh, w_fc, b_fc, PAIR, SCR);
  }

  // ---- final: h2 = PAIR[b][pos[0]]; attention, loss col 15 ----
  k_finsel<<<1, 128, 0, stream>>>(pos, xdst);
  k_qsc<<<dim3(24, 2), 256, 0, stream>>>(PAIR, xdst, Gbig, gb, SCT);
  k_sm<<<B, 256, 0, stream>>>(SCT, PAIR, xdst, v12, c0s, SC, A2, GI, b_ih, LOSS, 15, 0);
  k_writeout<<<(B * (R + 1) + B * 16 + 255) / 256, 256, 0, stream>>>(SC, LOSS, out);
}